// Round 1
// baseline (309.955 us; speedup 1.0000x reference)
//
#include <hip/hip_runtime.h>
#include <hip/hip_bf16.h>

typedef __attribute__((ext_vector_type(8))) short short8;
typedef __attribute__((ext_vector_type(4))) float f32x4;

// Problem constants
#define S_LEN 2048
#define E_DIM 1024
#define D_DIM 128
#define M_ROWS 8192   // B*S

static __device__ __forceinline__ unsigned short f2bf(float f){
  union { float f; unsigned int u; } v; v.f = f;
  unsigned int r = v.u + 0x7fffu + ((v.u >> 16) & 1u);
  return (unsigned short)(r >> 16);
}

// ---------------- kernel 1: x fp32 -> bf16 ----------------
__global__ void k_cvt_x(const float* __restrict__ x, unsigned short* __restrict__ xb){
  int i = (blockIdx.x * 256 + threadIdx.x) * 8;
  float4 a = *(const float4*)(x + i);
  float4 b = *(const float4*)(x + i + 4);
  unsigned short h[8];
  h[0]=f2bf(a.x); h[1]=f2bf(a.y); h[2]=f2bf(a.z); h[3]=f2bf(a.w);
  h[4]=f2bf(b.x); h[5]=f2bf(b.y); h[6]=f2bf(b.z); h[7]=f2bf(b.w);
  *(uint4*)(xb + i) = *(uint4*)h;
}

// ---------------- kernel 2: W -> Wt bf16 [p][d][e], bias concat ----------------
__global__ void k_prep_w(const float* __restrict__ Wq, const float* __restrict__ Wk,
                         const float* __restrict__ Wv,
                         const float* __restrict__ bq, const float* __restrict__ bk,
                         const float* __restrict__ bv,
                         unsigned short* __restrict__ Wt, float* __restrict__ bias){
  int gid = blockIdx.x * 256 + threadIdx.x;    // 0 .. 393215
  int p = gid >> 17;                            // / 131072
  int rem = gid & 131071;
  int d = rem >> 10, e = rem & 1023;
  const float* W = (p==0) ? Wq : ((p==1) ? Wk : Wv);
  Wt[gid] = f2bf(W[e*128 + d]);                 // Wt[p][d][e] = W[e][d]
  if (gid < 384){
    int pp = gid >> 7, dd = gid & 127;
    bias[gid] = (pp==0) ? bq[dd] : ((pp==1) ? bk[dd] : bv[dd]);
  }
}

// ---------------- kernel 3: fused QKV GEMM, bf16 MFMA ----------------
// C[8192,384] = Xb @ Wcat + bias; tile 128(M) x 128(N=one projection) x 64(K)
// p==0 -> Qb (scaled by 1/sqrt(D)), p==1 -> Kb, p==2 -> Vt[b][d][s] (transposed)
__global__ __launch_bounds__(256) void k_gemm_qkv(
    const unsigned short* __restrict__ Xb, const unsigned short* __restrict__ Wt,
    const float* __restrict__ bias,
    unsigned short* __restrict__ Qb, unsigned short* __restrict__ Kb,
    unsigned short* __restrict__ Vt){
  __shared__ __align__(16) unsigned short As[128*72];  // pad 64->72: rows offset 4 banks -> 2-way max (free)
  __shared__ __align__(16) unsigned short Bs[128*72];
  int tid = threadIdx.x;
  int m0 = blockIdx.x * 128;
  int p  = blockIdx.y;
  int w = tid >> 6, lane = tid & 63, quad = lane >> 4, l16 = lane & 15;
  int wm = (w >> 1) * 64, wn = (w & 1) * 64;
  f32x4 acc[4][4];
  #pragma unroll
  for (int i=0;i<4;i++)
    #pragma unroll
    for (int j=0;j<4;j++) acc[i][j] = (f32x4){0.f,0.f,0.f,0.f};

  const unsigned short* Wp = Wt + p * (128*1024);
  for (int k0 = 0; k0 < 1024; k0 += 64){
    #pragma unroll
    for (int it=0; it<4; it++){
      int lin = it*256 + tid;            // 0..1023 : 128 rows x 8 chunks of 8
      int row = lin >> 3, c8 = (lin & 7) * 8;
      *(uint4*)(As + row*72 + c8) = *(const uint4*)(Xb + (m0+row)*1024 + k0 + c8);
      *(uint4*)(Bs + row*72 + c8) = *(const uint4*)(Wp + row*1024 + k0 + c8);
    }
    __syncthreads();
    #pragma unroll
    for (int kk=0; kk<64; kk+=32){
      short8 af[4], bf[4];
      #pragma unroll
      for (int i=0;i<4;i++) af[i] = *(const short8*)(As + (wm + i*16 + l16)*72 + kk + quad*8);
      #pragma unroll
      for (int j=0;j<4;j++) bf[j] = *(const short8*)(Bs + (wn + j*16 + l16)*72 + kk + quad*8);
      #pragma unroll
      for (int i=0;i<4;i++)
        #pragma unroll
        for (int j=0;j<4;j++)
          acc[i][j] = __builtin_amdgcn_mfma_f32_16x16x32_bf16(af[i], bf[j], acc[i][j], 0,0,0);
    }
    __syncthreads();
  }
  const float qscale = 0.08838834764831845f;  // 1/sqrt(128), folded softmax scale
  #pragma unroll
  for (int i=0;i<4;i++){
    #pragma unroll
    for (int j=0;j<4;j++){
      int col = wn + j*16 + l16;           // 0..127 within projection
      float bv_ = bias[p*128 + col];
      #pragma unroll
      for (int r=0;r<4;r++){
        int row = m0 + wm + i*16 + quad*4 + r;   // C/D: row = quad*4+reg, col = lane&15
        float v = acc[i][j][r] + bv_;
        if (p == 0){
          Qb[row*128 + col] = f2bf(v * qscale);
        } else if (p == 1){
          Kb[row*128 + col] = f2bf(v);
        } else {
          int b = row >> 11, s = row & 2047;
          Vt[b*(128*2048) + col*2048 + s] = f2bf(v);
        }
      }
    }
  }
}

// ---------------- kernel 4: causal flash attention, bf16 MFMA ----------------
// block = 128 threads (2 waves); each wave owns 16 q-rows; block = 32 q-rows.
// KV tiles of 64 keys staged in LDS (K row-major, V transposed).
__global__ __launch_bounds__(128) void k_attn(
    const unsigned short* __restrict__ Qb, const unsigned short* __restrict__ Kb,
    const unsigned short* __restrict__ Vt, float* __restrict__ out){
  __shared__ __align__(16) unsigned short Ks[64*136];   // K tile [64 keys][128 d], pad->136
  __shared__ __align__(16) unsigned short Vs[128*72];   // V^T tile [128 d][64 keys], pad->72
  __shared__ __align__(16) unsigned short Ps[2*16*72];  // per-wave P round-trip
  int tid = threadIdx.x;
  int b  = blockIdx.y;
  int qt = 63 - blockIdx.x;          // heavy tiles first
  int q0 = qt * 32;
  int w = tid >> 6, lane = tid & 63, quad = lane >> 4, l16 = lane & 15;
  int qr0 = q0 + w*16;

  short8 aq[4];                       // Q fragments: A[m=l16][k=quad*8+j], k-chunks of 32
  #pragma unroll
  for (int kc=0; kc<4; kc++)
    aq[kc] = *(const short8*)(Qb + (b*2048 + qr0 + l16)*128 + kc*32 + quad*8);

  f32x4 o[8];
  #pragma unroll
  for (int i=0;i<8;i++) o[i] = (f32x4){0.f,0.f,0.f,0.f};
  float mrow[4] = {-1e30f,-1e30f,-1e30f,-1e30f};
  float lrow[4] = {0.f,0.f,0.f,0.f};

  int ntiles = (q0 >> 6) + 1;
  unsigned short* Pw = Ps + w*(16*72);

  for (int t=0; t<ntiles; t++){
    int t0 = t*64;
    #pragma unroll
    for (int it=0; it<8; it++){
      int lin = it*128 + tid;          // 0..1023
      int kr = lin >> 4, kc8 = (lin & 15)*8;   // K: 64 x 128
      *(uint4*)(Ks + kr*136 + kc8) = *(const uint4*)(Kb + (b*2048 + t0 + kr)*128 + kc8);
      int vr = lin >> 3, vc8 = (lin & 7)*8;    // Vt: 128 x 64
      *(uint4*)(Vs + vr*72 + vc8) = *(const uint4*)(Vt + b*(128*2048) + vr*2048 + t0 + vc8);
    }
    __syncthreads();

    // S = Q @ K^T  (16 q-rows x 64 keys per wave)
    f32x4 sc[4];
    #pragma unroll
    for (int nt=0;nt<4;nt++) sc[nt] = (f32x4){0.f,0.f,0.f,0.f};
    #pragma unroll
    for (int nt=0;nt<4;nt++)
      #pragma unroll
      for (int kc=0;kc<4;kc++){
        short8 bf = *(const short8*)(Ks + (nt*16 + l16)*136 + kc*32 + quad*8);
        sc[nt] = __builtin_amdgcn_mfma_f32_16x16x32_bf16(aq[kc], bf, sc[nt], 0,0,0);
      }

    // causal mask + row max (rows live as (quad*4+r), cols as l16+16*nt)
    float mt[4] = {-1e30f,-1e30f,-1e30f,-1e30f};
    #pragma unroll
    for (int nt=0;nt<4;nt++){
      int key = t0 + nt*16 + l16;
      #pragma unroll
      for (int r=0;r<4;r++){
        int qr = qr0 + quad*4 + r;
        float s = sc[nt][r];
        s = (key > qr) ? -1e30f : s;
        sc[nt][r] = s;
        mt[r] = fmaxf(mt[r], s);
      }
    }
    #pragma unroll
    for (int r=0;r<4;r++){
      mt[r] = fmaxf(mt[r], __shfl_xor(mt[r], 1));
      mt[r] = fmaxf(mt[r], __shfl_xor(mt[r], 2));
      mt[r] = fmaxf(mt[r], __shfl_xor(mt[r], 4));
      mt[r] = fmaxf(mt[r], __shfl_xor(mt[r], 8));
    }
    float alpha[4], rs[4];
    #pragma unroll
    for (int r=0;r<4;r++){
      float mn = fmaxf(mrow[r], mt[r]);
      alpha[r] = __expf(mrow[r] - mn);
      mrow[r] = mn;
      rs[r] = 0.f;
    }
    #pragma unroll
    for (int nt=0;nt<4;nt++)
      #pragma unroll
      for (int r=0;r<4;r++){
        float pv = __expf(sc[nt][r] - mrow[r]);
        sc[nt][r] = pv;
        rs[r] += pv;
      }
    #pragma unroll
    for (int r=0;r<4;r++){
      rs[r] += __shfl_xor(rs[r], 1);
      rs[r] += __shfl_xor(rs[r], 2);
      rs[r] += __shfl_xor(rs[r], 4);
      rs[r] += __shfl_xor(rs[r], 8);
      lrow[r] = lrow[r]*alpha[r] + rs[r];
    }
    #pragma unroll
    for (int i=0;i<8;i++)
      #pragma unroll
      for (int r=0;r<4;r++) o[i][r] *= alpha[r];

    // P: C-layout -> A-layout via per-wave LDS (no cross-wave hazard)
    #pragma unroll
    for (int nt=0;nt<4;nt++)
      #pragma unroll
      for (int r=0;r<4;r++)
        Pw[(quad*4+r)*72 + nt*16 + l16] = f2bf(sc[nt][r]);
    short8 ap[2];
    #pragma unroll
    for (int kc2=0; kc2<2; kc2++)
      ap[kc2] = *(const short8*)(Pw + l16*72 + kc2*32 + quad*8);

    // O += P @ V
    #pragma unroll
    for (int nt=0; nt<8; nt++)
      #pragma unroll
      for (int kc2=0;kc2<2;kc2++){
        short8 bf = *(const short8*)(Vs + (nt*16 + l16)*72 + kc2*32 + quad*8);
        o[nt] = __builtin_amdgcn_mfma_f32_16x16x32_bf16(ap[kc2], bf, o[nt], 0,0,0);
      }
    __syncthreads();   // protect Ks/Vs before next stage
  }

  #pragma unroll
  for (int r=0;r<4;r++){
    float inv = 1.0f / lrow[r];
    int row = b*2048 + qr0 + quad*4 + r;
    #pragma unroll
    for (int nt=0;nt<8;nt++)
      out[row*128 + nt*16 + l16] = o[nt][r] * inv;
  }
}

extern "C" void kernel_launch(void* const* d_in, const int* in_sizes, int n_in,
                              void* d_out, int out_size, void* d_ws, size_t ws_size,
                              hipStream_t stream) {
  const float* x  = (const float*)d_in[0];
  const float* Wq = (const float*)d_in[1];
  const float* bq = (const float*)d_in[2];
  const float* Wk = (const float*)d_in[3];
  const float* bk = (const float*)d_in[4];
  const float* Wv = (const float*)d_in[5];
  const float* bv = (const float*)d_in[6];
  char* ws = (char*)d_ws;
  unsigned short* Xb = (unsigned short*)(ws);               // 8192*1024*2   = 16,777,216
  unsigned short* Wt = (unsigned short*)(ws + 16777216);    // 3*128*1024*2  =    786,432
  float*          bias = (float*)(ws + 17563648);           // 384*4         =      1,536
  unsigned short* Qb = (unsigned short*)(ws + 17565184);    // 8192*128*2    =  2,097,152
  unsigned short* Kb = (unsigned short*)(ws + 19662336);    // 2,097,152
  unsigned short* Vt = (unsigned short*)(ws + 21759488);    // 2,097,152  (total ~22.8 MB)
  float* out = (float*)d_out;

  hipLaunchKernelGGL(k_cvt_x,   dim3(4096),  dim3(256), 0, stream, x, Xb);
  hipLaunchKernelGGL(k_prep_w,  dim3(1536),  dim3(256), 0, stream, Wq, Wk, Wv, bq, bk, bv, Wt, bias);
  hipLaunchKernelGGL(k_gemm_qkv,dim3(64,3),  dim3(256), 0, stream, Xb, Wt, bias, Qb, Kb, Vt);
  hipLaunchKernelGGL(k_attn,    dim3(64,4),  dim3(128), 0, stream, Qb, Kb, Vt, out);
}

// Round 2
// 177.575 us; speedup vs baseline: 1.7455x; 1.7455x over previous
//
#include <hip/hip_runtime.h>
#include <hip/hip_bf16.h>

typedef __attribute__((ext_vector_type(8))) short short8;
typedef __attribute__((ext_vector_type(4))) float f32x4;

// Problem constants
#define S_LEN 2048
#define E_DIM 1024
#define D_DIM 128
#define M_ROWS 8192   // B*S

static __device__ __forceinline__ unsigned short f2bf(float f){
  union { float f; unsigned int u; } v; v.f = f;
  unsigned int r = v.u + 0x7fffu + ((v.u >> 16) & 1u);
  return (unsigned short)(r >> 16);
}

// ---------------- kernel 1: x fp32 -> bf16 ----------------
__global__ void k_cvt_x(const float* __restrict__ x, unsigned short* __restrict__ xb){
  int i = (blockIdx.x * 256 + threadIdx.x) * 8;
  float4 a = *(const float4*)(x + i);
  float4 b = *(const float4*)(x + i + 4);
  unsigned short h[8];
  h[0]=f2bf(a.x); h[1]=f2bf(a.y); h[2]=f2bf(a.z); h[3]=f2bf(a.w);
  h[4]=f2bf(b.x); h[5]=f2bf(b.y); h[6]=f2bf(b.z); h[7]=f2bf(b.w);
  *(uint4*)(xb + i) = *(uint4*)h;
}

// ---------------- kernel 2: W -> Wt bf16 [p][d][e], bias concat ----------------
__global__ void k_prep_w(const float* __restrict__ Wq, const float* __restrict__ Wk,
                         const float* __restrict__ Wv,
                         const float* __restrict__ bq, const float* __restrict__ bk,
                         const float* __restrict__ bv,
                         unsigned short* __restrict__ Wt, float* __restrict__ bias){
  int gid = blockIdx.x * 256 + threadIdx.x;    // 0 .. 393215
  int p = gid >> 17;                            // / 131072
  int rem = gid & 131071;
  int d = rem >> 10, e = rem & 1023;
  const float* W = (p==0) ? Wq : ((p==1) ? Wk : Wv);
  Wt[gid] = f2bf(W[e*128 + d]);                 // Wt[p][d][e] = W[e][d]
  if (gid < 384){
    int pp = gid >> 7, dd = gid & 127;
    bias[gid] = (pp==0) ? bq[dd] : ((pp==1) ? bk[dd] : bv[dd]);
  }
}

// ---------------- kernel 3: fused QKV GEMM, bf16 MFMA ----------------
// C[8192,384] = Xb @ Wcat + bias; tile 128(M) x 128(N=one projection) x 64(K)
// p==0 -> Qb (scaled by 1/sqrt(D)), p==1 -> Kb, p==2 -> Vt[b][d][s] (transposed)
__global__ __launch_bounds__(256) void k_gemm_qkv(
    const unsigned short* __restrict__ Xb, const unsigned short* __restrict__ Wt,
    const float* __restrict__ bias,
    unsigned short* __restrict__ Qb, unsigned short* __restrict__ Kb,
    unsigned short* __restrict__ Vt){
  __shared__ __align__(16) unsigned short As[128*72];  // pad 64->72: rows offset 4 banks -> 2-way max (free)
  __shared__ __align__(16) unsigned short Bs[128*72];
  int tid = threadIdx.x;
  int m0 = blockIdx.x * 128;
  int p  = blockIdx.y;
  int w = tid >> 6, lane = tid & 63, quad = lane >> 4, l16 = lane & 15;
  int wm = (w >> 1) * 64, wn = (w & 1) * 64;
  f32x4 acc[4][4];
  #pragma unroll
  for (int i=0;i<4;i++)
    #pragma unroll
    for (int j=0;j<4;j++) acc[i][j] = (f32x4){0.f,0.f,0.f,0.f};

  const unsigned short* Wp = Wt + p * (128*1024);
  for (int k0 = 0; k0 < 1024; k0 += 64){
    #pragma unroll
    for (int it=0; it<4; it++){
      int lin = it*256 + tid;            // 0..1023 : 128 rows x 8 chunks of 8
      int row = lin >> 3, c8 = (lin & 7) * 8;
      *(uint4*)(As + row*72 + c8) = *(const uint4*)(Xb + (m0+row)*1024 + k0 + c8);
      *(uint4*)(Bs + row*72 + c8) = *(const uint4*)(Wp + row*1024 + k0 + c8);
    }
    __syncthreads();
    #pragma unroll
    for (int kk=0; kk<64; kk+=32){
      short8 af[4], bf[4];
      #pragma unroll
      for (int i=0;i<4;i++) af[i] = *(const short8*)(As + (wm + i*16 + l16)*72 + kk + quad*8);
      #pragma unroll
      for (int j=0;j<4;j++) bf[j] = *(const short8*)(Bs + (wn + j*16 + l16)*72 + kk + quad*8);
      #pragma unroll
      for (int i=0;i<4;i++)
        #pragma unroll
        for (int j=0;j<4;j++)
          acc[i][j] = __builtin_amdgcn_mfma_f32_16x16x32_bf16(af[i], bf[j], acc[i][j], 0,0,0);
    }
    __syncthreads();
  }
  const float qscale = 0.08838834764831845f;  // 1/sqrt(128), folded softmax scale
  #pragma unroll
  for (int i=0;i<4;i++){
    #pragma unroll
    for (int j=0;j<4;j++){
      int col = wn + j*16 + l16;           // 0..127 within projection
      float bv_ = bias[p*128 + col];
      #pragma unroll
      for (int r=0;r<4;r++){
        int row = m0 + wm + i*16 + quad*4 + r;   // C/D: row = quad*4+reg, col = lane&15
        float v = acc[i][j][r] + bv_;
        if (p == 0){
          Qb[row*128 + col] = f2bf(v * qscale);
        } else if (p == 1){
          Kb[row*128 + col] = f2bf(v);
        } else {
          int b = row >> 11, s = row & 2047;
          Vt[b*(128*2048) + col*2048 + s] = f2bf(v);
        }
      }
    }
  }
}

// ---------------- kernel 4: causal flash attention, kv-split, bf16 MFMA ----------------
// block = 512 threads = 8 waves; all waves share ONE 16-row q-tile; wave w
// processes KV tiles t ≡ w (mod 8) reading K/V directly from global (L2-resident).
// No barriers in the loop. End: 8 partial (O,m,l) combined through LDS.
__global__ __launch_bounds__(512, 4) void k_attn(
    const unsigned short* __restrict__ Qb, const unsigned short* __restrict__ Kb,
    const unsigned short* __restrict__ Vt, float* __restrict__ out){
  __shared__ __align__(16) float LDSo[8*16*128];   // 64 KB: per-wave partial O (+aliased P scratch)
  __shared__ float Lm[8*16];
  __shared__ float Ll[8*16];
  int tid = threadIdx.x;
  int b  = blockIdx.y;
  int qt = 127 - blockIdx.x;          // heavy q-tiles first
  int q0 = qt * 16;
  int w = tid >> 6, lane = tid & 63, quad = lane >> 4, l16 = lane & 15;

  // Q fragments: A[m=l16][k=quad*8+j], 4 k-chunks of 32 (D=128)
  short8 aq[4];
  #pragma unroll
  for (int kc=0; kc<4; kc++)
    aq[kc] = *(const short8*)(Qb + (b*2048 + q0 + l16)*128 + kc*32 + quad*8);

  f32x4 o[8];
  #pragma unroll
  for (int i=0;i<8;i++) o[i] = (f32x4){0.f,0.f,0.f,0.f};
  float mrow[4] = {-1e30f,-1e30f,-1e30f,-1e30f};
  float lrow[4] = {0.f,0.f,0.f,0.f};

  int T = (q0 >> 6) + 1;              // # 64-key tiles covering keys 0..q0+15
  unsigned short* Pw = (unsigned short*)(LDSo + w*2048);  // per-wave P scratch (aliased)

  const unsigned short* Kbase = Kb + b*2048*128;
  const unsigned short* Vbase = Vt + b*128*2048;

  for (int t = w; t < T; t += 8){
    int t0 = t*64;
    // S = Q @ K^T  (16 q-rows x 64 keys)
    f32x4 sc[4];
    #pragma unroll
    for (int nt=0;nt<4;nt++) sc[nt] = (f32x4){0.f,0.f,0.f,0.f};
    #pragma unroll
    for (int nt=0;nt<4;nt++)
      #pragma unroll
      for (int kc=0;kc<4;kc++){
        short8 bf = *(const short8*)(Kbase + (t0 + nt*16 + l16)*128 + kc*32 + quad*8);
        sc[nt] = __builtin_amdgcn_mfma_f32_16x16x32_bf16(aq[kc], bf, sc[nt], 0,0,0);
      }

    // causal mask + row max (rows = quad*4+r, key cols = t0 + nt*16 + l16)
    float mt[4] = {-1e30f,-1e30f,-1e30f,-1e30f};
    #pragma unroll
    for (int nt=0;nt<4;nt++){
      int key = t0 + nt*16 + l16;
      #pragma unroll
      for (int r=0;r<4;r++){
        int qr = q0 + quad*4 + r;
        float s = sc[nt][r];
        s = (key > qr) ? -1e30f : s;
        sc[nt][r] = s;
        mt[r] = fmaxf(mt[r], s);
      }
    }
    #pragma unroll
    for (int r=0;r<4;r++){
      mt[r] = fmaxf(mt[r], __shfl_xor(mt[r], 1));
      mt[r] = fmaxf(mt[r], __shfl_xor(mt[r], 2));
      mt[r] = fmaxf(mt[r], __shfl_xor(mt[r], 4));
      mt[r] = fmaxf(mt[r], __shfl_xor(mt[r], 8));
    }
    float alpha[4], rs[4];
    #pragma unroll
    for (int r=0;r<4;r++){
      float mn = fmaxf(mrow[r], mt[r]);
      alpha[r] = __expf(mrow[r] - mn);
      mrow[r] = mn;
      rs[r] = 0.f;
    }
    #pragma unroll
    for (int nt=0;nt<4;nt++)
      #pragma unroll
      for (int r=0;r<4;r++){
        float pv = __expf(sc[nt][r] - mrow[r]);
        sc[nt][r] = pv;
        rs[r] += pv;
      }
    #pragma unroll
    for (int r=0;r<4;r++){
      rs[r] += __shfl_xor(rs[r], 1);
      rs[r] += __shfl_xor(rs[r], 2);
      rs[r] += __shfl_xor(rs[r], 4);
      rs[r] += __shfl_xor(rs[r], 8);
      lrow[r] = lrow[r]*alpha[r] + rs[r];
    }
    #pragma unroll
    for (int i=0;i<8;i++)
      #pragma unroll
      for (int r=0;r<4;r++) o[i][r] *= alpha[r];

    // P: C-layout -> A-layout via per-wave LDS scratch (same-wave dep, no barrier)
    #pragma unroll
    for (int nt=0;nt<4;nt++)
      #pragma unroll
      for (int r=0;r<4;r++)
        Pw[(quad*4+r)*72 + nt*16 + l16] = f2bf(sc[nt][r]);
    short8 ap[2];
    #pragma unroll
    for (int kc2=0; kc2<2; kc2++)
      ap[kc2] = *(const short8*)(Pw + l16*72 + kc2*32 + quad*8);

    // O += P @ V   (V^T layout: B[n=d][k=key] contiguous in key)
    #pragma unroll
    for (int nt=0; nt<8; nt++)
      #pragma unroll
      for (int kc2=0;kc2<2;kc2++){
        short8 bf = *(const short8*)(Vbase + (nt*16 + l16)*2048 + t0 + kc2*32 + quad*8);
        o[nt] = __builtin_amdgcn_mfma_f32_16x16x32_bf16(ap[kc2], bf, o[nt], 0,0,0);
      }
  }

  // deposit per-wave partials
  #pragma unroll
  for (int i=0;i<8;i++)
    #pragma unroll
    for (int r=0;r<4;r++)
      LDSo[w*2048 + (quad*4+r)*128 + i*16 + l16] = o[i][r];
  if (l16 == 0){
    #pragma unroll
    for (int r=0;r<4;r++){
      Lm[w*16 + quad*4 + r] = mrow[r];
      Ll[w*16 + quad*4 + r] = lrow[r];
    }
  }
  __syncthreads();

  // combine 8 partials: out = (Σ e_w O_w) / (Σ e_w l_w),  e_w = exp(m_w - m*)
  int row = tid >> 5;              // 0..15
  int c0  = (tid & 31) * 4;        // 0..124
  float m = -1e30f;
  #pragma unroll
  for (int w8=0; w8<8; w8++) m = fmaxf(m, Lm[w8*16 + row]);
  float acc0=0.f, acc1=0.f, acc2=0.f, acc3=0.f, lsum=0.f;
  #pragma unroll
  for (int w8=0; w8<8; w8++){
    float e = __expf(Lm[w8*16 + row] - m);
    lsum += Ll[w8*16 + row] * e;
    f32x4 ov = *(const f32x4*)(LDSo + w8*2048 + row*128 + c0);
    acc0 += ov[0]*e; acc1 += ov[1]*e; acc2 += ov[2]*e; acc3 += ov[3]*e;
  }
  float inv = 1.0f / lsum;
  float4 res = {acc0*inv, acc1*inv, acc2*inv, acc3*inv};
  *(float4*)(out + (b*2048 + q0 + row)*128 + c0) = res;
}

extern "C" void kernel_launch(void* const* d_in, const int* in_sizes, int n_in,
                              void* d_out, int out_size, void* d_ws, size_t ws_size,
                              hipStream_t stream) {
  const float* x  = (const float*)d_in[0];
  const float* Wq = (const float*)d_in[1];
  const float* bq = (const float*)d_in[2];
  const float* Wk = (const float*)d_in[3];
  const float* bk = (const float*)d_in[4];
  const float* Wv = (const float*)d_in[5];
  const float* bv = (const float*)d_in[6];
  char* ws = (char*)d_ws;
  unsigned short* Xb = (unsigned short*)(ws);               // 8192*1024*2   = 16,777,216
  unsigned short* Wt = (unsigned short*)(ws + 16777216);    // 3*128*1024*2  =    786,432
  float*          bias = (float*)(ws + 17563648);           // 384*4         =      1,536
  unsigned short* Qb = (unsigned short*)(ws + 17565184);    // 8192*128*2    =  2,097,152
  unsigned short* Kb = (unsigned short*)(ws + 19662336);    // 2,097,152
  unsigned short* Vt = (unsigned short*)(ws + 21759488);    // 2,097,152  (total ~22.8 MB)
  float* out = (float*)d_out;

  hipLaunchKernelGGL(k_cvt_x,   dim3(4096),  dim3(256), 0, stream, x, Xb);
  hipLaunchKernelGGL(k_prep_w,  dim3(1536),  dim3(256), 0, stream, Wq, Wk, Wv, bq, bk, bv, Wt, bias);
  hipLaunchKernelGGL(k_gemm_qkv,dim3(64,3),  dim3(256), 0, stream, Xb, Wt, bias, Qb, Kb, Vt);
  hipLaunchKernelGGL(k_attn,    dim3(128,4), dim3(512), 0, stream, Qb, Kb, Vt, out);
}

// Round 3
// 154.717 us; speedup vs baseline: 2.0034x; 1.1477x over previous
//
#include <hip/hip_runtime.h>
#include <hip/hip_bf16.h>

typedef __attribute__((ext_vector_type(8))) short short8;
typedef __attribute__((ext_vector_type(4))) float f32x4;

static __device__ __forceinline__ unsigned short f2bf(float f){
  union { float f; unsigned int u; } v; v.f = f;
  unsigned int r = v.u + 0x7fffu + ((v.u >> 16) & 1u);
  return (unsigned short)(r >> 16);
}

static __device__ __forceinline__ void load_lds16(const unsigned short* g, unsigned short* l){
  __builtin_amdgcn_global_load_lds(
      (const __attribute__((address_space(1))) unsigned int*)(g),
      (__attribute__((address_space(3))) unsigned int*)(l), 16, 0, 0);
}

// ---------------- kernel 1: x fp32 -> bf16 ----------------
__global__ void k_cvt_x(const float* __restrict__ x, unsigned short* __restrict__ xb){
  int i = (blockIdx.x * 256 + threadIdx.x) * 8;
  float4 a = *(const float4*)(x + i);
  float4 b = *(const float4*)(x + i + 4);
  unsigned short h[8];
  h[0]=f2bf(a.x); h[1]=f2bf(a.y); h[2]=f2bf(a.z); h[3]=f2bf(a.w);
  h[4]=f2bf(b.x); h[5]=f2bf(b.y); h[6]=f2bf(b.z); h[7]=f2bf(b.w);
  *(uint4*)(xb + i) = *(uint4*)h;
}

// ---------------- kernel 2: W -> Wt bf16 [p][d][e], bias concat ----------------
__global__ void k_prep_w(const float* __restrict__ Wq, const float* __restrict__ Wk,
                         const float* __restrict__ Wv,
                         const float* __restrict__ bq, const float* __restrict__ bk,
                         const float* __restrict__ bv,
                         unsigned short* __restrict__ Wt, float* __restrict__ bias){
  int gid = blockIdx.x * 256 + threadIdx.x;    // 0 .. 393215
  int p = gid >> 17;
  int rem = gid & 131071;
  int d = rem >> 10, e = rem & 1023;
  const float* W = (p==0) ? Wq : ((p==1) ? Wk : Wv);
  Wt[gid] = f2bf(W[e*128 + d]);                 // Wt[p][d][e] = W[e][d]
  if (gid < 384){
    int pp = gid >> 7, dd = gid & 127;
    bias[gid] = (pp==0) ? bq[dd] : ((pp==1) ? bk[dd] : bv[dd]);
  }
}

// ---------------- kernel 3: fused QKV GEMM, bf16 MFMA, global_load_lds staging ---
// C[8192,384] = Xb @ Wcat + bias; tile 128(M) x 128(N=one projection) x 64(K)
// Epilogue writes MFMA-fragment-linear swizzled layouts:
//   Qsw/Ksw: [rowtile16][kc(4)][quad(4)][l16(16)][8]   (2048 elems / 16-row tile)
//   Vsw:     [b][t64][nt(8)][kc2(2)][quad(4)][l16(16)][8] (8192 elems / 64-key tile)
__global__ __launch_bounds__(256) void k_gemm_qkv(
    const unsigned short* __restrict__ Xb, const unsigned short* __restrict__ Wt,
    const float* __restrict__ bias,
    unsigned short* __restrict__ Qsw, unsigned short* __restrict__ Ksw,
    unsigned short* __restrict__ Vsw){
  __shared__ __align__(16) unsigned short As[128*64];   // unpadded: global_load_lds needs contiguity
  __shared__ __align__(16) unsigned short Bs[128*64];
  int tid = threadIdx.x;
  int m0 = blockIdx.x * 128;
  int p  = blockIdx.y;
  int w = tid >> 6, lane = tid & 63, quad = lane >> 4, l16 = lane & 15;
  int wm = (w >> 1) * 64, wn = (w & 1) * 64;
  f32x4 acc[4][4];
  #pragma unroll
  for (int i=0;i<4;i++)
    #pragma unroll
    for (int j=0;j<4;j++) acc[i][j] = (f32x4){0.f,0.f,0.f,0.f};

  const unsigned short* Wp = Wt + p * (128*1024);
  // wave w stages rows [w*32, w*32+32) of both tiles; one instr = 8 rows (64 lanes x 16B)
  int rowbase = w * 32;
  const unsigned short* Ag = Xb + (m0 + rowbase + (lane>>3))*1024 + (lane&7)*8;
  const unsigned short* Bg = Wp + (rowbase + (lane>>3))*1024 + (lane&7)*8;
  unsigned short* Al = As + rowbase*64;   // wave-uniform LDS base; HW adds lane*16B
  unsigned short* Bl = Bs + rowbase*64;

  for (int k0 = 0; k0 < 1024; k0 += 64){
    #pragma unroll
    for (int s8=0; s8<4; s8++){
      load_lds16(Ag + k0 + s8*8192, Al + s8*512);
      load_lds16(Bg + k0 + s8*8192, Bl + s8*512);
    }
    __syncthreads();   // drains vmcnt (global_load_lds) + lgkm
    #pragma unroll
    for (int kk=0; kk<64; kk+=32){
      short8 af[4], bf[4];
      #pragma unroll
      for (int i=0;i<4;i++) af[i] = *(const short8*)(As + (wm + i*16 + l16)*64 + kk + quad*8);
      #pragma unroll
      for (int j=0;j<4;j++) bf[j] = *(const short8*)(Bs + (wn + j*16 + l16)*64 + kk + quad*8);
      #pragma unroll
      for (int i=0;i<4;i++)
        #pragma unroll
        for (int j=0;j<4;j++)
          acc[i][j] = __builtin_amdgcn_mfma_f32_16x16x32_bf16(af[i], bf[j], acc[i][j], 0,0,0);
    }
    __syncthreads();
  }
  const float qscale = 0.08838834764831845f;  // 1/sqrt(128) folded into Q
  #pragma unroll
  for (int i=0;i<4;i++){
    #pragma unroll
    for (int j=0;j<4;j++){
      int c = wn + j*16 + l16;             // 0..127 (d for Q/K/V)
      float bv_ = bias[p*128 + c];
      #pragma unroll
      for (int r=0;r<4;r++){
        int row = m0 + wm + i*16 + quad*4 + r;   // global row (C/D: row=quad*4+reg, col=l16)
        float v = acc[i][j][r] + bv_;
        if (p == 0){
          int rt = row >> 4, m = row & 15;
          int kc = c >> 5, q2 = (c >> 3) & 3, jj = c & 7;
          Qsw[rt*2048 + kc*512 + q2*128 + m*8 + jj] = f2bf(v * qscale);
        } else if (p == 1){
          int kt = row >> 4, n = row & 15;
          int kc = c >> 5, q2 = (c >> 3) & 3, jj = c & 7;
          Ksw[kt*2048 + kc*512 + q2*128 + n*8 + jj] = f2bf(v);
        } else {
          int b = row >> 11, s = row & 2047;
          int t64 = s >> 6, srem = s & 63;
          int kc2 = srem >> 5, q2 = (srem >> 3) & 3, jj = srem & 7;
          int nt = c >> 4, l2 = c & 15;
          Vsw[(b*32 + t64)*8192 + nt*1024 + kc2*512 + q2*128 + l2*8 + jj] = f2bf(v);
        }
      }
    }
  }
}

// ---------------- kernel 4: causal flash attention, kv-split, coalesced frags ---
// block = 512 threads = 8 waves sharing one 16-row q-tile; wave w does KV tiles
// t ≡ w (mod 8). All fragment loads are contiguous 1KB wave loads (swizzled layouts).
__global__ __launch_bounds__(512, 4) void k_attn(
    const unsigned short* __restrict__ Qsw, const unsigned short* __restrict__ Ksw,
    const unsigned short* __restrict__ Vsw, float* __restrict__ out){
  __shared__ __align__(16) float LDSo[8*16*128];   // 64 KB partial O (+aliased P scratch)
  __shared__ float Lm[8*16];
  __shared__ float Ll[8*16];
  int tid = threadIdx.x;
  int b  = blockIdx.y;
  int qt = 127 - blockIdx.x;          // heavy q-tiles first
  int q0 = qt * 16;
  int w = tid >> 6, lane = tid & 63, quad = lane >> 4, l16 = lane & 15;

  short8 aq[4];
  #pragma unroll
  for (int kc=0; kc<4; kc++)
    aq[kc] = *(const short8*)(Qsw + (b*128 + qt)*2048 + kc*512 + lane*8);

  f32x4 o[8];
  #pragma unroll
  for (int i=0;i<8;i++) o[i] = (f32x4){0.f,0.f,0.f,0.f};
  float mrow[4] = {-1e30f,-1e30f,-1e30f,-1e30f};
  float lrow[4] = {0.f,0.f,0.f,0.f};

  int T = (q0 >> 6) + 1;
  unsigned short* Pw = (unsigned short*)(LDSo + w*2048);

  const unsigned short* Kb = Ksw + b*128*2048;
  const unsigned short* Vb = Vsw + b*32*8192;

  for (int t = w; t < T; t += 8){
    int t0 = t*64;
    // S = Q @ K^T
    f32x4 sc[4];
    #pragma unroll
    for (int nt=0;nt<4;nt++) sc[nt] = (f32x4){0.f,0.f,0.f,0.f};
    #pragma unroll
    for (int nt=0;nt<4;nt++){
      const unsigned short* Kt = Kb + ((t0>>4) + nt)*2048 + lane*8;
      #pragma unroll
      for (int kc=0;kc<4;kc++){
        short8 bf = *(const short8*)(Kt + kc*512);
        sc[nt] = __builtin_amdgcn_mfma_f32_16x16x32_bf16(aq[kc], bf, sc[nt], 0,0,0);
      }
    }

    // causal mask + online softmax (rows = quad*4+r, key cols = t0 + nt*16 + l16)
    float mt[4] = {-1e30f,-1e30f,-1e30f,-1e30f};
    #pragma unroll
    for (int nt=0;nt<4;nt++){
      int key = t0 + nt*16 + l16;
      #pragma unroll
      for (int r=0;r<4;r++){
        int qr = q0 + quad*4 + r;
        float s = sc[nt][r];
        s = (key > qr) ? -1e30f : s;
        sc[nt][r] = s;
        mt[r] = fmaxf(mt[r], s);
      }
    }
    #pragma unroll
    for (int r=0;r<4;r++){
      mt[r] = fmaxf(mt[r], __shfl_xor(mt[r], 1));
      mt[r] = fmaxf(mt[r], __shfl_xor(mt[r], 2));
      mt[r] = fmaxf(mt[r], __shfl_xor(mt[r], 4));
      mt[r] = fmaxf(mt[r], __shfl_xor(mt[r], 8));
    }
    float alpha[4], rs[4];
    #pragma unroll
    for (int r=0;r<4;r++){
      float mn = fmaxf(mrow[r], mt[r]);
      alpha[r] = __expf(mrow[r] - mn);
      mrow[r] = mn;
      rs[r] = 0.f;
    }
    #pragma unroll
    for (int nt=0;nt<4;nt++)
      #pragma unroll
      for (int r=0;r<4;r++){
        float pv = __expf(sc[nt][r] - mrow[r]);
        sc[nt][r] = pv;
        rs[r] += pv;
      }
    #pragma unroll
    for (int r=0;r<4;r++){
      rs[r] += __shfl_xor(rs[r], 1);
      rs[r] += __shfl_xor(rs[r], 2);
      rs[r] += __shfl_xor(rs[r], 4);
      rs[r] += __shfl_xor(rs[r], 8);
      lrow[r] = lrow[r]*alpha[r] + rs[r];
    }
    #pragma unroll
    for (int i=0;i<8;i++)
      #pragma unroll
      for (int r=0;r<4;r++) o[i][r] *= alpha[r];

    // P: C-layout -> A-layout via per-wave LDS scratch (same-wave dep, no barrier)
    #pragma unroll
    for (int nt=0;nt<4;nt++)
      #pragma unroll
      for (int r=0;r<4;r++)
        Pw[(quad*4+r)*72 + nt*16 + l16] = f2bf(sc[nt][r]);
    short8 ap[2];
    #pragma unroll
    for (int kc2=0; kc2<2; kc2++)
      ap[kc2] = *(const short8*)(Pw + l16*72 + kc2*32 + quad*8);

    // O += P @ V  (Vsw fragment-linear: contiguous 1KB per (nt,kc2))
    const unsigned short* Vt0 = Vb + (t0>>6)*8192 + lane*8;
    #pragma unroll
    for (int nt=0; nt<8; nt++)
      #pragma unroll
      for (int kc2=0;kc2<2;kc2++){
        short8 bf = *(const short8*)(Vt0 + nt*1024 + kc2*512);
        o[nt] = __builtin_amdgcn_mfma_f32_16x16x32_bf16(ap[kc2], bf, o[nt], 0,0,0);
      }
  }

  // deposit per-wave partials
  #pragma unroll
  for (int i=0;i<8;i++)
    #pragma unroll
    for (int r=0;r<4;r++)
      LDSo[w*2048 + (quad*4+r)*128 + i*16 + l16] = o[i][r];
  if (l16 == 0){
    #pragma unroll
    for (int r=0;r<4;r++){
      Lm[w*16 + quad*4 + r] = mrow[r];
      Ll[w*16 + quad*4 + r] = lrow[r];
    }
  }
  __syncthreads();

  // combine 8 partials: out = (Σ e_w O_w) / (Σ e_w l_w),  e_w = exp(m_w - m*)
  int row = tid >> 5;              // 0..15
  int c0  = (tid & 31) * 4;        // 0..124
  float m = -1e30f;
  #pragma unroll
  for (int w8=0; w8<8; w8++) m = fmaxf(m, Lm[w8*16 + row]);
  float acc0=0.f, acc1=0.f, acc2=0.f, acc3=0.f, lsum=0.f;
  #pragma unroll
  for (int w8=0; w8<8; w8++){
    float e = __expf(Lm[w8*16 + row] - m);
    lsum += Ll[w8*16 + row] * e;
    f32x4 ov = *(const f32x4*)(LDSo + w8*2048 + row*128 + c0);
    acc0 += ov[0]*e; acc1 += ov[1]*e; acc2 += ov[2]*e; acc3 += ov[3]*e;
  }
  float inv = 1.0f / lsum;
  float4 res = {acc0*inv, acc1*inv, acc2*inv, acc3*inv};
  *(float4*)(out + (b*2048 + q0 + row)*128 + c0) = res;
}

extern "C" void kernel_launch(void* const* d_in, const int* in_sizes, int n_in,
                              void* d_out, int out_size, void* d_ws, size_t ws_size,
                              hipStream_t stream) {
  const float* x  = (const float*)d_in[0];
  const float* Wq = (const float*)d_in[1];
  const float* bq = (const float*)d_in[2];
  const float* Wk = (const float*)d_in[3];
  const float* bk = (const float*)d_in[4];
  const float* Wv = (const float*)d_in[5];
  const float* bv = (const float*)d_in[6];
  char* ws = (char*)d_ws;
  unsigned short* Xb = (unsigned short*)(ws);               // 16,777,216 B
  unsigned short* Wt = (unsigned short*)(ws + 16777216);    //    786,432 B
  float*          bias = (float*)(ws + 17563648);           //      1,536 B
  unsigned short* Qsw = (unsigned short*)(ws + 17565184);   //  2,097,152 B
  unsigned short* Ksw = (unsigned short*)(ws + 19662336);   //  2,097,152 B
  unsigned short* Vsw = (unsigned short*)(ws + 21759488);   //  2,097,152 B
  float* out = (float*)d_out;

  hipLaunchKernelGGL(k_cvt_x,   dim3(4096),  dim3(256), 0, stream, x, Xb);
  hipLaunchKernelGGL(k_prep_w,  dim3(1536),  dim3(256), 0, stream, Wq, Wk, Wv, bq, bk, bv, Wt, bias);
  hipLaunchKernelGGL(k_gemm_qkv,dim3(64,3),  dim3(256), 0, stream, Xb, Wt, bias, Qsw, Ksw, Vsw);
  hipLaunchKernelGGL(k_attn,    dim3(128,4), dim3(512), 0, stream, Qsw, Ksw, Vsw, out);
}